// Round 14
// baseline (309.313 us; speedup 1.0000x reference)
//
#include <hip/hip_runtime.h>
#include <hip/hip_bf16.h>

typedef unsigned short u16;
typedef unsigned int u32;
typedef __attribute__((ext_vector_type(8))) short short8;
typedef __attribute__((ext_vector_type(4))) float f32x4;

#define L 4096
#define DMODEL 2048
#define NHEADS 16
#define DHEAD 128
// 1/sqrt(128) * log2(e): attention scale folded into Q projection, exp2 domain
#define QSCALE (0.08838834764831845f * 1.44269504088896340f)

__device__ __forceinline__ u16 f2bf(float f){
  union { float f; unsigned int i; } v; v.f = f;
  unsigned int u = v.i;
  u += 0x7fffu + ((u >> 16) & 1u);
  return (u16)(u >> 16);
}

__device__ __forceinline__ u32 cvtpk(float lo, float hi){
  u32 d;
  asm("v_cvt_pk_bf16_f32 %0, %1, %2" : "=v"(d) : "v"(lo), "v"(hi));
  return d;
}

// Merged cast: y=0 -> X (L*DMODEL f32), y=1..4 -> weight y-1 (DMODEL^2 f32).
__global__ void cast_all_kernel(const float* __restrict__ X, u16* __restrict__ Xo,
                                const float* __restrict__ w0, const float* __restrict__ w1,
                                const float* __restrict__ w2, const float* __restrict__ w3,
                                u16* __restrict__ o0, u16* __restrict__ o1,
                                u16* __restrict__ o2, u16* __restrict__ o3){
  const int y = blockIdx.y;
  const float* in = (y == 0) ? X : (y == 1) ? w0 : (y == 2) ? w1 : (y == 3) ? w2 : w3;
  u16* out = (y == 0) ? Xo : (y == 1) ? o0 : (y == 2) ? o1 : (y == 3) ? o2 : o3;
  const int n = (y == 0) ? (L * DMODEL) : (DMODEL * DMODEL);
  int stride = gridDim.x * blockDim.x * 4;
  for (int j = (blockIdx.x * blockDim.x + threadIdx.x) * 4; j < n; j += stride){
    float4 f = *reinterpret_cast<const float4*>(in + j);
    ushort4 o;
    o.x = f2bf(f.x); o.y = f2bf(f.y); o.z = f2bf(f.z); o.w = f2bf(f.w);
    *reinterpret_cast<ushort4*>(out + j) = o;
  }
}

__device__ __forceinline__ void gl_lds16(void* lds, const void* g){
  __builtin_amdgcn_global_load_lds(
      (const __attribute__((address_space(1))) unsigned int*)g,
      (__attribute__((address_space(3))) unsigned int*)lds, 16, 0, 0);
}

// ---------------------------------------------------------------------------
// GEMM: C = A @ W^T (+bias). 128x128 tile, BK=32, 4 waves (2Mx2N, 64x64/wave),
// 3 x 16KB LDS buffers, prefetch distance 2, single barrier per K-step,
// counted vmcnt(4), 3 blocks/CU. 64B k-rows: 2-way-free swizzle
// byte ^= (((row>>1)&3)<<4) on stage-source AND frag-read.
// MODE 0: Q/K bf16 [H][L][128]; MODE 1: V^T bf16 [H][128][L]; MODE 2: f32 out.
// ---------------------------------------------------------------------------
#define GBUF 8192   // u16 per buffer (16KB): A 8KB + B 8KB

template<int MODE>
__device__ __forceinline__ void gemm128(const u16* __restrict__ A, const u16* __restrict__ W,
                                        const float* __restrict__ bias, void* __restrict__ outp,
                                        float cscale, int bx, int by, u16* gsm){
  const int tid = threadIdx.x;
  const int wid = tid >> 6, lane = tid & 63;
  const int wm = wid >> 1, wn = wid & 1;
  const int g = lane >> 4, r = lane & 15;

  // Staging: thread -> row = tid>>2 (64 rows per 4KB issue), 16B slot (tid&3),
  // source byte pre-swizzled to match the read-side XOR.
  const int srow = tid >> 2;
  const int sc = ((tid & 3) * 16) ^ (((srow >> 1) & 3) << 4);
  const u16* Ag = A + ((size_t)(bx * 128) + srow) * DMODEL + (sc >> 1);
  const u16* Bg = W + ((size_t)(by * 128) + srow) * DMODEL + (sc >> 1);

  f32x4 acc[4][4];
  #pragma unroll
  for (int m = 0; m < 4; ++m)
    #pragma unroll
    for (int n = 0; n < 4; ++n) acc[m][n] = (f32x4){0,0,0,0};

  const int NK = DMODEL / 32;   // 64 K-steps

  auto STAGE = [&](int b, int tk){
    char* ab = (char*)(gsm + b * GBUF);
    char* bb = (char*)(gsm + b * GBUF + 4096);
    const int ke = tk * 32;
    #pragma unroll
    for (int i = 0; i < 2; ++i)
      gl_lds16(ab + i * 4096 + tid * 16 - lane * 16 + lane * 16 - tid * 16 + tid * 16,  // tid*16 base
               (const char*)(Ag + (size_t)(i * 64) * DMODEL + ke));
    #pragma unroll
    for (int i = 0; i < 2; ++i)
      gl_lds16(bb + i * 4096 + tid * 16,
               (const char*)(Bg + (size_t)(i * 64) * DMODEL + ke));
  };
  // NOTE: dest must be wave-uniform base + lane*16; tid*16 = wid*1024 + lane*16. OK.

  STAGE(0, 0); STAGE(1, 1);

  int cur = 0;
  for (int t = 0; t < NK; ++t){
    if (t < NK - 1) asm volatile("s_waitcnt vmcnt(4)" ::: "memory");
    else            asm volatile("s_waitcnt vmcnt(0)" ::: "memory");
    __builtin_amdgcn_sched_barrier(0);
    __builtin_amdgcn_s_barrier();
    __builtin_amdgcn_sched_barrier(0);

    if (t + 2 < NK){
      int nb = cur + 2; if (nb >= 3) nb -= 3;
      STAGE(nb, t + 2);
    }

    const char* ab = (const char*)(gsm + cur * GBUF);
    const char* bb = (const char*)(gsm + cur * GBUF + 4096);

    short8 af[4], bf[4];
    #pragma unroll
    for (int mt = 0; mt < 4; ++mt){
      const int ar = wm * 64 + mt * 16 + r;
      af[mt] = *reinterpret_cast<const short8*>(
          ab + ar * 64 + ((g * 16) ^ (((ar >> 1) & 3) << 4)));
    }
    #pragma unroll
    for (int nt = 0; nt < 4; ++nt){
      const int br = wn * 64 + nt * 16 + r;
      bf[nt] = *reinterpret_cast<const short8*>(
          bb + br * 64 + ((g * 16) ^ (((br >> 1) & 3) << 4)));
    }

    __builtin_amdgcn_s_setprio(1);
    #pragma unroll
    for (int mt = 0; mt < 4; ++mt)
      #pragma unroll
      for (int nt = 0; nt < 4; ++nt)
        acc[mt][nt] = __builtin_amdgcn_mfma_f32_16x16x32_bf16(af[mt], bf[nt], acc[mt][nt], 0, 0, 0);
    __builtin_amdgcn_s_setprio(0);

    ++cur; if (cur == 3) cur = 0;
  }

  #pragma unroll
  for (int nt = 0; nt < 4; ++nt){
    const int col = by * 128 + wn * 64 + nt * 16 + r;
    const float bv = bias[col & (DMODEL - 1)];
    #pragma unroll
    for (int mt = 0; mt < 4; ++mt){
      #pragma unroll
      for (int qi = 0; qi < 4; ++qi){
        const int row = bx * 128 + wm * 64 + mt * 16 + g * 4 + qi;
        if (MODE == 0){
          ((u16*)outp)[(size_t)((col & (DMODEL-1)) >> 7) * (L * DHEAD) + (size_t)row * DHEAD + (col & 127)]
              = f2bf((acc[mt][nt][qi] + bv) * cscale);
        } else if (MODE == 1){
          ((u16*)outp)[(size_t)((col & (DMODEL-1)) >> 7) * (DHEAD * L) + (size_t)(col & 127) * L + row]
              = f2bf(acc[mt][nt][qi] + bv);
        } else {
          ((float*)outp)[(size_t)row * DMODEL + col] = acc[mt][nt][qi] + bv;
        }
      }
    }
  }
}

// Fused Q/K/V projection: 1536 blocks (1-D), XCD-chunked. id -> (bx 0..31, by 0..47).
__global__ __launch_bounds__(256, 3) void gemm_qkv(const u16* __restrict__ A,
    const u16* __restrict__ Wq, const u16* __restrict__ Wk, const u16* __restrict__ Wv,
    const float* __restrict__ bq, const float* __restrict__ bk, const float* __restrict__ bv,
    u16* __restrict__ Qb, u16* __restrict__ Kb, u16* __restrict__ Vtb){
  extern __shared__ u16 gsm[];
  int id = blockIdx.x;
  int nid = (id & 7) * 192 + (id >> 3);     // bijective: 1536 % 8 == 0
  int by = nid >> 5, bx = nid & 31;
  int sel = by >> 4, byl = by & 15;
  const u16* W      = (sel == 0) ? Wq : (sel == 1) ? Wk : Wv;
  const float* bias = (sel == 0) ? bq : (sel == 1) ? bk : bv;
  if (sel < 2)
    gemm128<0>(A, W, bias, (sel == 0) ? (void*)Qb : (void*)Kb,
               (sel == 0) ? QSCALE : 1.0f, bx, byl, gsm);
  else
    gemm128<1>(A, W, bias, (void*)Vtb, 1.0f, bx, byl, gsm);
}

// Output projection: 512 blocks (1-D), XCD-chunked. id -> (bx 0..31, by 0..15).
__global__ __launch_bounds__(256, 3) void gemm_o(const u16* __restrict__ A, const u16* __restrict__ W,
                                                 const float* __restrict__ bias, float* __restrict__ outp){
  extern __shared__ u16 gsm[];
  int id = blockIdx.x;
  int nid = (id & 7) * 64 + (id >> 3);      // bijective: 512 % 8 == 0
  int by = nid >> 5, bx = nid & 31;
  gemm128<2>(A, W, bias, (void*)outp, 1.0f, bx, by, gsm);
}

// ---------------------------------------------------------------------------
// Attention (unchanged from R13): KVBLK=64, 512 blocks (2/CU), 4 waves,
// strip pair (j, 63-j), K/V double-buffered, single barrier per tile,
// fixed-reference softmax, in-register P via cvt_pk + permlane swaps.
// LDS 64 KiB: K 2x16K + V 2x16K.
// ---------------------------------------------------------------------------

__device__ __forceinline__ void stage_K64(u16* buf, const u16* Kh, int kv0, int wid, int lane){
  #pragma unroll
  for (int i = 0; i < 4; ++i){
    int ib = (wid * 4 + i) * 1024;
    int off = ib + lane * 16;
    int row = off >> 8;
    int c = off & 255;
    int sc = c ^ ((row & 7) << 4);
    gl_lds16((char*)buf + ib, (const char*)(Kh + (size_t)(kv0 + row) * DHEAD) + sc);
  }
}

__device__ __forceinline__ void stage_V64(u16* buf, const u16* Vh, int kv0, int wid, int lane){
  #pragma unroll
  for (int i = 0; i < 4; ++i){
    int ib = (wid * 4 + i) * 1024;
    int off = ib + lane * 16;
    int row = off >> 7;
    int c = off & 127;
    int sc = c ^ ((row & 7) << 4);
    gl_lds16((char*)buf + ib, (const char*)(Vh + (size_t)row * L + kv0) + sc);
  }
}

// Fixed-reference softmax (S-16 via MFMA C-init, exp2 domain) producing the
// PV A-fragments directly in registers. paw[ks][w]: word w = gs*2+h of frag ks.
__device__ __forceinline__ void sm_R(f32x4 (&s)[4], float &l, bool dg, int qrow,
                                     int kv0, int g, u32 (&paw)[2][4]){
  if (dg){
    #pragma unroll
    for (int cb = 0; cb < 4; ++cb){
      int kvb = kv0 + cb * 16 + g * 4;
      #pragma unroll
      for (int e = 0; e < 4; ++e)
        if (kvb + e > qrow) s[cb][e] = -1e30f;
    }
  }
  float rs = 0.f;
  u32 pk[4][2];
  #pragma unroll
  for (int cb = 0; cb < 4; ++cb){
    float p0 = __builtin_amdgcn_exp2f(s[cb][0]);
    float p1 = __builtin_amdgcn_exp2f(s[cb][1]);
    float p2 = __builtin_amdgcn_exp2f(s[cb][2]);
    float p3 = __builtin_amdgcn_exp2f(s[cb][3]);
    rs += (p0 + p1) + (p2 + p3);
    pk[cb][0] = cvtpk(p0, p1);
    pk[cb][1] = cvtpk(p2, p3);
  }
  rs += __shfl_xor(rs, 16);
  rs += __shfl_xor(rs, 32);
  l += rs;
  #pragma unroll
  for (int ks = 0; ks < 2; ++ks){
    #pragma unroll
    for (int h = 0; h < 2; ++h){
      u32 a = pk[ks * 2][h], b = pk[ks * 2 + 1][h];
      asm volatile("v_permlane32_swap_b32 %0, %1" : "+v"(a), "+v"(b));
      asm volatile("v_permlane16_swap_b32 %0, %1" : "+v"(a), "+v"(b));
      paw[ks][h] = a;
      paw[ks][2 + h] = b;
    }
  }
}

__global__ __launch_bounds__(256, 2) void attn_kernel(const u16* __restrict__ Q, const u16* __restrict__ Km,
                                                      const u16* __restrict__ Vt, u16* __restrict__ Ob,
                                                      const int* __restrict__ is_causal_p){
  extern __shared__ u16 smem[];
  u16* Ks  = smem;            // 2 x 8192 u16 = 32 KiB
  u16* Vsm = smem + 16384;    // 2 x 8192 u16 = 32 KiB

  const int lane = threadIdx.x & 63, wid = threadIdx.x >> 6;
  const int g = lane >> 4, r = lane & 15;

  int lg = (blockIdx.x & 7) * 64 + (blockIdx.x >> 3);
  int head = lg >> 5;
  int raw = lg & 31;
  int j = (head & 1) ? (31 - raw) : raw;
  const int jA = j, jB = 63 - j;
  const int causal = *is_causal_p;
  const int nt = causal ? (jB + 1) : 64;

  const u16* Qh = Q  + (size_t)head * L * DHEAD;
  const u16* Kh = Km + (size_t)head * L * DHEAD;
  const u16* Vh = Vt + (size_t)head * DHEAD * L;

  const int rowA = 64 * jA + wid * 16;
  const int rowB = 64 * jB + wid * 16;

  short8 qf[2][4];
  #pragma unroll
  for (int kb = 0; kb < 4; ++kb){
    qf[0][kb] = *reinterpret_cast<const short8*>(&Qh[(size_t)(rowA + r) * DHEAD + kb * 32 + g * 8]);
    qf[1][kb] = *reinterpret_cast<const short8*>(&Qh[(size_t)(rowB + r) * DHEAD + kb * 32 + g * 8]);
  }

  f32x4 o[2][8];
  #pragma unroll
  for (int m = 0; m < 2; ++m)
    #pragma unroll
    for (int db = 0; db < 8; ++db) o[m][db] = (f32x4){0.f, 0.f, 0.f, 0.f};
  float lA = 0.f, lB = 0.f;

  stage_K64(Ks,  Kh, 0, wid, lane);
  stage_V64(Vsm, Vh, 0, wid, lane);

  for (int t = 0; t < nt; ++t){
    const int kv0 = t * 64;
    const bool actA = (!causal) || (t <= jA);
    const bool dgA = causal && (t == jA);
    const bool dgB = causal && (t == jB);

    asm volatile("s_waitcnt vmcnt(0)" ::: "memory");
    __builtin_amdgcn_sched_barrier(0);
    __builtin_amdgcn_s_barrier();
    __builtin_amdgcn_sched_barrier(0);

    if (t + 1 < nt){
      stage_K64(Ks  + ((t + 1) & 1) * 8192, Kh, kv0 + 64, wid, lane);
      stage_V64(Vsm + ((t + 1) & 1) * 8192, Vh, kv0 + 64, wid, lane);
    }

    const char* Kb = (const char*)(Ks  + (t & 1) * 8192);
    const char* Vb = (const char*)(Vsm + (t & 1) * 8192);

    f32x4 s[2][4];
    #pragma unroll
    for (int m = 0; m < 2; ++m)
      #pragma unroll
      for (int cb = 0; cb < 4; ++cb) s[m][cb] = (f32x4){-16.f, -16.f, -16.f, -16.f};
    __builtin_amdgcn_s_setprio(1);
    #pragma unroll
    for (int cb = 0; cb < 4; ++cb){
      const int rr = cb * 16 + r;
      short8 kf[4];
      #pragma unroll
      for (int kb = 0; kb < 4; ++kb)
        kf[kb] = *reinterpret_cast<const short8*>(
            Kb + rr * 256 + ((kb * 64 + g * 16) ^ ((rr & 7) << 4)));
      if (actA){
        #pragma unroll
        for (int kb = 0; kb < 4; ++kb)
          s[0][cb] = __builtin_amdgcn_mfma_f32_16x16x32_bf16(kf[kb], qf[0][kb], s[0][cb], 0, 0, 0);
      }
      #pragma unroll
      for (int kb = 0; kb < 4; ++kb)
        s[1][cb] = __builtin_amdgcn_mfma_f32_16x16x32_bf16(kf[kb], qf[1][kb], s[1][cb], 0, 0, 0);
    }
    __builtin_amdgcn_s_setprio(0);

    u32 pawA[2][4], pawB[2][4];
    if (actA) sm_R(s[0], lA, dgA, rowA + r, kv0, g, pawA);
    sm_R(s[1], lB, dgB, rowB + r, kv0, g, pawB);

    __builtin_amdgcn_s_setprio(1);
    #pragma unroll
    for (int st = 0; st < 2; ++st){
      union { u32 u[4]; short8 v; } pa0, pa1;
      #pragma unroll
      for (int w = 0; w < 4; ++w){ pa0.u[w] = pawA[st][w]; pa1.u[w] = pawB[st][w]; }
      #pragma unroll
      for (int db = 0; db < 8; ++db){
        const int rv = db * 16 + r;
        short8 vf = *reinterpret_cast<const short8*>(
            Vb + rv * 128 + (((st * 32 + g * 8) * 2) ^ ((rv & 7) << 4)));
        if (actA)
          o[0][db] = __builtin_amdgcn_mfma_f32_16x16x32_bf16(pa0.v, vf, o[0][db], 0, 0, 0);
        o[1][db] = __builtin_amdgcn_mfma_f32_16x16x32_bf16(pa1.v, vf, o[1][db], 0, 0, 0);
      }
    }
    __builtin_amdgcn_s_setprio(0);
  }

  #pragma unroll
  for (int m = 0; m < 2; ++m){
    const int rbase = m ? rowB : rowA;
    const float lv = m ? lB : lA;
    float lb[4];
    #pragma unroll
    for (int qi = 0; qi < 4; ++qi) lb[qi] = __shfl(lv, g * 4 + qi);
    #pragma unroll
    for (int db = 0; db < 8; ++db)
      #pragma unroll
      for (int qi = 0; qi < 4; ++qi){
        float val = o[m][db][qi] / lb[qi];
        int qrow = rbase + g * 4 + qi;
        Ob[(size_t)qrow * DMODEL + head * DHEAD + db * 16 + r] = f2bf(val);
      }
  }
}

extern "C" void kernel_launch(void* const* d_in, const int* in_sizes, int n_in,
                              void* d_out, int out_size, void* d_ws, size_t ws_size,
                              hipStream_t stream){
  const float* X  = (const float*)d_in[0];
  const float* Wq = (const float*)d_in[1];
  const float* bq = (const float*)d_in[2];
  const float* Wk = (const float*)d_in[3];
  const float* bk = (const float*)d_in[4];
  const float* Wv = (const float*)d_in[5];
  const float* bv = (const float*)d_in[6];
  const float* Wo = (const float*)d_in[7];
  const float* bo = (const float*)d_in[8];
  const int*   isc = (const int*)d_in[9];

  char* ws = (char*)d_ws;
  u16* Xb  = (u16*)(ws);              // 16 MiB, reused as Ob after attention
  u16* Qb  = (u16*)(ws + 16777216);
  u16* Kb  = (u16*)(ws + 33554432);
  u16* Vtb = (u16*)(ws + 50331648);
  u16* Wqb = (u16*)(ws + 67108864);
  u16* Wkb = (u16*)(ws + 75497472);
  u16* Wvb = (u16*)(ws + 83886080);
  u16* Wob = (u16*)(ws + 92274688);
  u16* Ob  = Xb;

  (void)hipFuncSetAttribute(reinterpret_cast<const void*>(attn_kernel),
                            hipFuncAttributeMaxDynamicSharedMemorySize, 65536);
  (void)hipFuncSetAttribute(reinterpret_cast<const void*>(gemm_qkv),
                            hipFuncAttributeMaxDynamicSharedMemorySize, 49152);
  (void)hipFuncSetAttribute(reinterpret_cast<const void*>(gemm_o),
                            hipFuncAttributeMaxDynamicSharedMemorySize, 49152);

  cast_all_kernel<<<dim3(1024, 5), 256, 0, stream>>>(X, Xb, Wq, Wk, Wv, Wo,
                                                     Wqb, Wkb, Wvb, Wob);

  gemm_qkv<<<1536, 256, 49152, stream>>>(Xb, Wqb, Wkb, Wvb, bq, bk, bv, Qb, Kb, Vtb);

  attn_kernel<<<512, 256, 65536, stream>>>(Qb, Kb, Vtb, Ob, isc);

  gemm_o<<<512, 256, 49152, stream>>>(Ob, Wob, bo, (float*)d_out);
}

// Round 15
// 282.378 us; speedup vs baseline: 1.0954x; 1.0954x over previous
//
#include <hip/hip_runtime.h>
#include <hip/hip_bf16.h>

typedef unsigned short u16;
typedef unsigned int u32;
typedef __attribute__((ext_vector_type(8))) short short8;
typedef __attribute__((ext_vector_type(4))) float f32x4;

#define L 4096
#define DMODEL 2048
#define NHEADS 16
#define DHEAD 128
// 1/sqrt(128) * log2(e): attention scale folded into Q projection, exp2 domain
#define QSCALE (0.08838834764831845f * 1.44269504088896340f)

__device__ __forceinline__ u16 f2bf(float f){
  union { float f; unsigned int i; } v; v.f = f;
  unsigned int u = v.i;
  u += 0x7fffu + ((u >> 16) & 1u);
  return (u16)(u >> 16);
}

__device__ __forceinline__ u32 cvtpk(float lo, float hi){
  u32 d;
  asm("v_cvt_pk_bf16_f32 %0, %1, %2" : "=v"(d) : "v"(lo), "v"(hi));
  return d;
}

// Merged cast: y=0 -> X (L*DMODEL f32), y=1..4 -> weight y-1 (DMODEL^2 f32).
__global__ void cast_all_kernel(const float* __restrict__ X, u16* __restrict__ Xo,
                                const float* __restrict__ w0, const float* __restrict__ w1,
                                const float* __restrict__ w2, const float* __restrict__ w3,
                                u16* __restrict__ o0, u16* __restrict__ o1,
                                u16* __restrict__ o2, u16* __restrict__ o3){
  const int y = blockIdx.y;
  const float* in = (y == 0) ? X : (y == 1) ? w0 : (y == 2) ? w1 : (y == 3) ? w2 : w3;
  u16* out = (y == 0) ? Xo : (y == 1) ? o0 : (y == 2) ? o1 : (y == 3) ? o2 : o3;
  const int n = (y == 0) ? (L * DMODEL) : (DMODEL * DMODEL);
  int stride = gridDim.x * blockDim.x * 4;
  for (int j = (blockIdx.x * blockDim.x + threadIdx.x) * 4; j < n; j += stride){
    float4 f = *reinterpret_cast<const float4*>(in + j);
    ushort4 o;
    o.x = f2bf(f.x); o.y = f2bf(f.y); o.z = f2bf(f.z); o.w = f2bf(f.w);
    *reinterpret_cast<ushort4*>(out + j) = o;
  }
}

__device__ __forceinline__ void gl_lds16(void* lds, const void* g){
  __builtin_amdgcn_global_load_lds(
      (const __attribute__((address_space(1))) unsigned int*)g,
      (__attribute__((address_space(3))) unsigned int*)lds, 16, 0, 0);
}

// ---------------------------------------------------------------------------
// GEMM: C = A @ W^T (+bias). 256x128 tile (R13-proven), BK=32, 8 waves as
// 4Mx2N (wave-tile 64x64 -> 16 ds_reads per 32-MFMA-equivalent, -20% LDS
// traffic vs 2Mx4N), 3 x 24KB LDS buffers (72KB -> 2 blocks/CU), prefetch
// distance 2, single barrier per K-step, counted vmcnt(3).
// 64B k-rows: bank = 16(row&1)+4g -> 8-way conflict unless swizzled.
// Fix: byte ^= ((row>>1)&3)<<4 on stage-source AND frag-read (2-way = free).
// MODE 0: Q/K bf16 [H][L][128]; MODE 1: V^T bf16 [H][128][L]; MODE 2: f32 out.
// ---------------------------------------------------------------------------
#define GBUF 12288   // u16 per buffer (24KB): A 16KB + B 8KB

template<int MODE>
__device__ __forceinline__ void gemm_core(const u16* __restrict__ A, const u16* __restrict__ W,
                                          const float* __restrict__ bias, void* __restrict__ outp,
                                          float cscale, int bx, int by, u16* gsm){
  const int tid = threadIdx.x;
  const int wid = tid >> 6, lane = tid & 63;
  const int wm = wid >> 1, wn = wid & 1;     // 4M x 2N wave grid
  const int g = lane >> 4, r = lane & 15;

  // Staging: each issue = 8KB = 128 rows x 64B; thread -> row tid>>2, 16B slot tid&3.
  // Source byte pre-swizzled to match the read-side XOR (involutive).
  const int srow = tid >> 2;
  const int sc = ((tid & 3) * 16) ^ (((srow >> 1) & 3) << 4);
  const u16* Ag = A + ((size_t)(bx * 256) + srow) * DMODEL + (sc >> 1);
  const u16* Bg = W + ((size_t)(by * 128) + srow) * DMODEL + (sc >> 1);
  const int ldsw = wid * 1024;   // per-wave byte base within an 8KB issue

  f32x4 acc[4][4];
  #pragma unroll
  for (int m = 0; m < 4; ++m)
    #pragma unroll
    for (int n = 0; n < 4; ++n) acc[m][n] = (f32x4){0,0,0,0};

  const int NK = DMODEL / 32;   // 64 K-steps

  auto STAGE = [&](int b, int tk){
    char* ab = (char*)(gsm + b * GBUF);           // 16KB: A 256 rows x 64B
    char* bb = (char*)(gsm + b * GBUF + 8192);    // 8KB:  B 128 rows x 64B
    const int ke = tk * 32;
    gl_lds16(ab + ldsw,        (const char*)(Ag + ke));
    gl_lds16(ab + 8192 + ldsw, (const char*)(Ag + (size_t)128 * DMODEL + ke));
    gl_lds16(bb + ldsw,        (const char*)(Bg + ke));
  };

  STAGE(0, 0); STAGE(1, 1);

  int cur = 0;
  for (int t = 0; t < NK; ++t){
    if (t < NK - 1) asm volatile("s_waitcnt vmcnt(3)" ::: "memory");
    else            asm volatile("s_waitcnt vmcnt(0)" ::: "memory");
    __builtin_amdgcn_sched_barrier(0);
    __builtin_amdgcn_s_barrier();
    __builtin_amdgcn_sched_barrier(0);

    if (t + 2 < NK){
      int nb = cur + 2; if (nb >= 3) nb -= 3;
      STAGE(nb, t + 2);
    }

    const char* ab = (const char*)(gsm + cur * GBUF);
    const char* bb = (const char*)(gsm + cur * GBUF + 8192);

    short8 af[4], bf[4];
    #pragma unroll
    for (int mt = 0; mt < 4; ++mt){
      const int ar = wm * 64 + mt * 16 + r;
      af[mt] = *reinterpret_cast<const short8*>(
          ab + ar * 64 + ((g * 16) ^ (((ar >> 1) & 3) << 4)));
    }
    #pragma unroll
    for (int nt = 0; nt < 4; ++nt){
      const int br = wn * 64 + nt * 16 + r;
      bf[nt] = *reinterpret_cast<const short8*>(
          bb + br * 64 + ((g * 16) ^ (((br >> 1) & 3) << 4)));
    }

    __builtin_amdgcn_s_setprio(1);
    #pragma unroll
    for (int mt = 0; mt < 4; ++mt)
      #pragma unroll
      for (int nt = 0; nt < 4; ++nt)
        acc[mt][nt] = __builtin_amdgcn_mfma_f32_16x16x32_bf16(af[mt], bf[nt], acc[mt][nt], 0, 0, 0);
    __builtin_amdgcn_s_setprio(0);

    ++cur; if (cur == 3) cur = 0;
  }

  #pragma unroll
  for (int nt = 0; nt < 4; ++nt){
    const int col = by * 128 + wn * 64 + nt * 16 + r;
    const float bv = bias[col];
    #pragma unroll
    for (int mt = 0; mt < 4; ++mt){
      #pragma unroll
      for (int qi = 0; qi < 4; ++qi){
        const int row = bx * 256 + wm * 64 + mt * 16 + g * 4 + qi;
        if (MODE == 0){
          ((u16*)outp)[(size_t)(col >> 7) * (L * DHEAD) + (size_t)row * DHEAD + (col & 127)]
              = f2bf((acc[mt][nt][qi] + bv) * cscale);
        } else if (MODE == 1){
          ((u16*)outp)[(size_t)(col >> 7) * (DHEAD * L) + (size_t)(col & 127) * L + row]
              = f2bf(acc[mt][nt][qi] + bv);
        } else {
          ((float*)outp)[(size_t)row * DMODEL + col] = acc[mt][nt][qi] + bv;
        }
      }
    }
  }
}

// Fused Q/K/V projection: grid (16, 48); blockIdx.y>>4 selects {Q,K,V}.
__global__ __launch_bounds__(512, 4) void gemm_qkv(const u16* __restrict__ A,
    const u16* __restrict__ Wq, const u16* __restrict__ Wk, const u16* __restrict__ Wv,
    const float* __restrict__ bq, const float* __restrict__ bk, const float* __restrict__ bv,
    u16* __restrict__ Qb, u16* __restrict__ Kb, u16* __restrict__ Vtb){
  extern __shared__ u16 gsm[];
  const int sel = blockIdx.y >> 4;
  const int byl = blockIdx.y & 15;
  const u16* W      = (sel == 0) ? Wq : (sel == 1) ? Wk : Wv;
  const float* bias = (sel == 0) ? bq : (sel == 1) ? bk : bv;
  if (sel < 2)
    gemm_core<0>(A, W, bias, (sel == 0) ? (void*)Qb : (void*)Kb,
                 (sel == 0) ? QSCALE : 1.0f, blockIdx.x, byl, gsm);
  else
    gemm_core<1>(A, W, bias, (void*)Vtb, 1.0f, blockIdx.x, byl, gsm);
}

// Output projection: f32 epilogue. grid (16, 16).
__global__ __launch_bounds__(512, 4) void gemm_o(const u16* __restrict__ A, const u16* __restrict__ W,
                                                 const float* __restrict__ bias, float* __restrict__ outp){
  extern __shared__ u16 gsm[];
  gemm_core<2>(A, W, bias, (void*)outp, 1.0f, blockIdx.x, blockIdx.y, gsm);
}

// ---------------------------------------------------------------------------
// Attention (unchanged from R13 — best measured): KVBLK=64, 512 blocks (2/CU),
// 4 waves, strip pair (j, 63-j), K/V double-buffered, single barrier per tile,
// fixed-reference softmax, in-register P via cvt_pk + permlane swaps.
// LDS 64 KiB: K 2x16K + V 2x16K.
// ---------------------------------------------------------------------------

__device__ __forceinline__ void stage_K64(u16* buf, const u16* Kh, int kv0, int wid, int lane){
  #pragma unroll
  for (int i = 0; i < 4; ++i){
    int ib = (wid * 4 + i) * 1024;
    int off = ib + lane * 16;
    int row = off >> 8;
    int c = off & 255;
    int sc = c ^ ((row & 7) << 4);
    gl_lds16((char*)buf + ib, (const char*)(Kh + (size_t)(kv0 + row) * DHEAD) + sc);
  }
}

__device__ __forceinline__ void stage_V64(u16* buf, const u16* Vh, int kv0, int wid, int lane){
  #pragma unroll
  for (int i = 0; i < 4; ++i){
    int ib = (wid * 4 + i) * 1024;
    int off = ib + lane * 16;
    int row = off >> 7;
    int c = off & 127;
    int sc = c ^ ((row & 7) << 4);
    gl_lds16((char*)buf + ib, (const char*)(Vh + (size_t)row * L + kv0) + sc);
  }
}

// Fixed-reference softmax (S-16 via MFMA C-init, exp2 domain) producing the
// PV A-fragments directly in registers. paw[ks][w]: word w = gs*2+h of frag ks.
__device__ __forceinline__ void sm_R(f32x4 (&s)[4], float &l, bool dg, int qrow,
                                     int kv0, int g, u32 (&paw)[2][4]){
  if (dg){
    #pragma unroll
    for (int cb = 0; cb < 4; ++cb){
      int kvb = kv0 + cb * 16 + g * 4;
      #pragma unroll
      for (int e = 0; e < 4; ++e)
        if (kvb + e > qrow) s[cb][e] = -1e30f;
    }
  }
  float rs = 0.f;
  u32 pk[4][2];
  #pragma unroll
  for (int cb = 0; cb < 4; ++cb){
    float p0 = __builtin_amdgcn_exp2f(s[cb][0]);
    float p1 = __builtin_amdgcn_exp2f(s[cb][1]);
    float p2 = __builtin_amdgcn_exp2f(s[cb][2]);
    float p3 = __builtin_amdgcn_exp2f(s[cb][3]);
    rs += (p0 + p1) + (p2 + p3);
    pk[cb][0] = cvtpk(p0, p1);
    pk[cb][1] = cvtpk(p2, p3);
  }
  rs += __shfl_xor(rs, 16);
  rs += __shfl_xor(rs, 32);
  l += rs;
  #pragma unroll
  for (int ks = 0; ks < 2; ++ks){
    #pragma unroll
    for (int h = 0; h < 2; ++h){
      u32 a = pk[ks * 2][h], b = pk[ks * 2 + 1][h];
      asm volatile("v_permlane32_swap_b32 %0, %1" : "+v"(a), "+v"(b));
      asm volatile("v_permlane16_swap_b32 %0, %1" : "+v"(a), "+v"(b));
      paw[ks][h] = a;
      paw[ks][2 + h] = b;
    }
  }
}

__global__ __launch_bounds__(256, 2) void attn_kernel(const u16* __restrict__ Q, const u16* __restrict__ Km,
                                                      const u16* __restrict__ Vt, u16* __restrict__ Ob,
                                                      const int* __restrict__ is_causal_p){
  extern __shared__ u16 smem[];
  u16* Ks  = smem;            // 2 x 8192 u16 = 32 KiB
  u16* Vsm = smem + 16384;    // 2 x 8192 u16 = 32 KiB

  const int lane = threadIdx.x & 63, wid = threadIdx.x >> 6;
  const int g = lane >> 4, r = lane & 15;

  int lg = (blockIdx.x & 7) * 64 + (blockIdx.x >> 3);
  int head = lg >> 5;
  int raw = lg & 31;
  int j = (head & 1) ? (31 - raw) : raw;
  const int jA = j, jB = 63 - j;
  const int causal = *is_causal_p;
  const int nt = causal ? (jB + 1) : 64;

  const u16* Qh = Q  + (size_t)head * L * DHEAD;
  const u16* Kh = Km + (size_t)head * L * DHEAD;
  const u16* Vh = Vt + (size_t)head * DHEAD * L;

  const int rowA = 64 * jA + wid * 16;
  const int rowB = 64 * jB + wid * 16;

  short8 qf[2][4];
  #pragma unroll
  for (int kb = 0; kb < 4; ++kb){
    qf[0][kb] = *reinterpret_cast<const short8*>(&Qh[(size_t)(rowA + r) * DHEAD + kb * 32 + g * 8]);
    qf[1][kb] = *reinterpret_cast<const short8*>(&Qh[(size_t)(rowB + r) * DHEAD + kb * 32 + g * 8]);
  }

  f32x4 o[2][8];
  #pragma unroll
  for (int m = 0; m < 2; ++m)
    #pragma unroll
    for (int db = 0; db < 8; ++db) o[m][db] = (f32x4){0.f, 0.f, 0.f, 0.f};
  float lA = 0.f, lB = 0.f;

  stage_K64(Ks,  Kh, 0, wid, lane);
  stage_V64(Vsm, Vh, 0, wid, lane);

  for (int t = 0; t < nt; ++t){
    const int kv0 = t * 64;
    const bool actA = (!causal) || (t <= jA);
    const bool dgA = causal && (t == jA);
    const bool dgB = causal && (t == jB);

    asm volatile("s_waitcnt vmcnt(0)" ::: "memory");
    __builtin_amdgcn_sched_barrier(0);
    __builtin_amdgcn_s_barrier();
    __builtin_amdgcn_sched_barrier(0);

    if (t + 1 < nt){
      stage_K64(Ks  + ((t + 1) & 1) * 8192, Kh, kv0 + 64, wid, lane);
      stage_V64(Vsm + ((t + 1) & 1) * 8192, Vh, kv0 + 64, wid, lane);
    }

    const char* Kb = (const char*)(Ks  + (t & 1) * 8192);
    const char* Vb = (const char*)(Vsm + (t & 1) * 8192);

    f32x4 s[2][4];
    #pragma unroll
    for (int m = 0; m < 2; ++m)
      #pragma unroll
      for (int cb = 0; cb < 4; ++cb) s[m][cb] = (f32x4){-16.f, -16.f, -16.f, -16.f};
    __builtin_amdgcn_s_setprio(1);
    #pragma unroll
    for (int cb = 0; cb < 4; ++cb){
      const int rr = cb * 16 + r;
      short8 kf[4];
      #pragma unroll
      for (int kb = 0; kb < 4; ++kb)
        kf[kb] = *reinterpret_cast<const short8*>(
            Kb + rr * 256 + ((kb * 64 + g * 16) ^ ((rr & 7) << 4)));
      if (actA){
        #pragma unroll
        for (int kb = 0; kb < 4; ++kb)
          s[0][cb] = __builtin_amdgcn_mfma_f32_16x16x32_bf16(kf[kb], qf[0][kb], s[0][cb], 0, 0, 0);
      }
      #pragma unroll
      for (int kb = 0; kb < 4; ++kb)
        s[1][cb] = __builtin_amdgcn_mfma_f32_16x16x32_bf16(kf[kb], qf[1][kb], s[1][cb], 0, 0, 0);
    }
    __builtin_amdgcn_s_setprio(0);

    u32 pawA[2][4], pawB[2][4];
    if (actA) sm_R(s[0], lA, dgA, rowA + r, kv0, g, pawA);
    sm_R(s[1], lB, dgB, rowB + r, kv0, g, pawB);

    __builtin_amdgcn_s_setprio(1);
    #pragma unroll
    for (int st = 0; st < 2; ++st){
      union { u32 u[4]; short8 v; } pa0, pa1;
      #pragma unroll
      for (int w = 0; w < 4; ++w){ pa0.u[w] = pawA[st][w]; pa1.u[w] = pawB[st][w]; }
      #pragma unroll
      for (int db = 0; db < 8; ++db){
        const int rv = db * 16 + r;
        short8 vf = *reinterpret_cast<const short8*>(
            Vb + rv * 128 + (((st * 32 + g * 8) * 2) ^ ((rv & 7) << 4)));
        if (actA)
          o[0][db] = __builtin_amdgcn_mfma_f32_16x16x32_bf16(pa0.v, vf, o[0][db], 0, 0, 0);
        o[1][db] = __builtin_amdgcn_mfma_f32_16x16x32_bf16(pa1.v, vf, o[1][db], 0, 0, 0);
      }
    }
    __builtin_amdgcn_s_setprio(0);
  }

  #pragma unroll
  for (int m = 0; m < 2; ++m){
    const int rbase = m ? rowB : rowA;
    const float lv = m ? lB : lA;
    float lb[4];
    #pragma unroll
    for (int qi = 0; qi < 4; ++qi) lb[qi] = __shfl(lv, g * 4 + qi);
    #pragma unroll
    for (int db = 0; db < 8; ++db)
      #pragma unroll
      for (int qi = 0; qi < 4; ++qi){
        float val = o[m][db][qi] / lb[qi];
        int qrow = rbase + g * 4 + qi;
        Ob[(size_t)qrow * DMODEL + head * DHEAD + db * 16 + r] = f2bf(val);
      }
  }
}

extern "C" void kernel_launch(void* const* d_in, const int* in_sizes, int n_in,
                              void* d_out, int out_size, void* d_ws, size_t ws_size,
                              hipStream_t stream){
  const float* X  = (const float*)d_in[0];
  const float* Wq = (const float*)d_in[1];
  const float* bq = (const float*)d_in[2];
  const float* Wk = (const float*)d_in[3];
  const float* bk = (const float*)d_in[4];
  const float* Wv = (const float*)d_in[5];
  const float* bv = (const float*)d_in[6];
  const float* Wo = (const float*)d_in[7];
  const float* bo = (const float*)d_in[8];
  const int*   isc = (const int*)d_in[9];

  char* ws = (char*)d_ws;
  u16* Xb  = (u16*)(ws);              // 16 MiB, reused as Ob after attention
  u16* Qb  = (u16*)(ws + 16777216);
  u16* Kb  = (u16*)(ws + 33554432);
  u16* Vtb = (u16*)(ws + 50331648);
  u16* Wqb = (u16*)(ws + 67108864);
  u16* Wkb = (u16*)(ws + 75497472);
  u16* Wvb = (u16*)(ws + 83886080);
  u16* Wob = (u16*)(ws + 92274688);
  u16* Ob  = Xb;

  (void)hipFuncSetAttribute(reinterpret_cast<const void*>(attn_kernel),
                            hipFuncAttributeMaxDynamicSharedMemorySize, 65536);
  (void)hipFuncSetAttribute(reinterpret_cast<const void*>(gemm_qkv),
                            hipFuncAttributeMaxDynamicSharedMemorySize, 73728);
  (void)hipFuncSetAttribute(reinterpret_cast<const void*>(gemm_o),
                            hipFuncAttributeMaxDynamicSharedMemorySize, 73728);

  cast_all_kernel<<<dim3(1024, 5), 256, 0, stream>>>(X, Xb, Wq, Wk, Wv, Wo,
                                                     Wqb, Wkb, Wvb, Wob);

  gemm_qkv<<<dim3(16, 48), 512, 73728, stream>>>(Xb, Wqb, Wkb, Wvb, bq, bk, bv, Qb, Kb, Vtb);

  attn_kernel<<<512, 256, 65536, stream>>>(Qb, Kb, Vtb, Ob, isc);

  gemm_o<<<dim3(16, 16), 512, 73728, stream>>>(Ob, Wob, bo, (float*)d_out);
}

// Round 16
// 278.752 us; speedup vs baseline: 1.1096x; 1.0130x over previous
//
#include <hip/hip_runtime.h>
#include <hip/hip_bf16.h>

typedef unsigned short u16;
typedef unsigned int u32;
typedef __attribute__((ext_vector_type(8))) short short8;
typedef __attribute__((ext_vector_type(4))) float f32x4;

#define L 4096
#define DMODEL 2048
#define NHEADS 16
#define DHEAD 128
// 1/sqrt(128) * log2(e): attention scale folded into Q projection, exp2 domain
#define QSCALE (0.08838834764831845f * 1.44269504088896340f)

__device__ __forceinline__ u16 f2bf(float f){
  union { float f; unsigned int i; } v; v.f = f;
  unsigned int u = v.i;
  u += 0x7fffu + ((u >> 16) & 1u);
  return (u16)(u >> 16);
}

__device__ __forceinline__ u32 cvtpk(float lo, float hi){
  u32 d;
  asm("v_cvt_pk_bf16_f32 %0, %1, %2" : "=v"(d) : "v"(lo), "v"(hi));
  return d;
}

// Merged cast: y=0 -> X (L*DMODEL f32), y=1..4 -> weight y-1 (DMODEL^2 f32).
__global__ void cast_all_kernel(const float* __restrict__ X, u16* __restrict__ Xo,
                                const float* __restrict__ w0, const float* __restrict__ w1,
                                const float* __restrict__ w2, const float* __restrict__ w3,
                                u16* __restrict__ o0, u16* __restrict__ o1,
                                u16* __restrict__ o2, u16* __restrict__ o3){
  const int y = blockIdx.y;
  const float* in = (y == 0) ? X : (y == 1) ? w0 : (y == 2) ? w1 : (y == 3) ? w2 : w3;
  u16* out = (y == 0) ? Xo : (y == 1) ? o0 : (y == 2) ? o1 : (y == 3) ? o2 : o3;
  const int n = (y == 0) ? (L * DMODEL) : (DMODEL * DMODEL);
  int stride = gridDim.x * blockDim.x * 4;
  for (int j = (blockIdx.x * blockDim.x + threadIdx.x) * 4; j < n; j += stride){
    float4 f = *reinterpret_cast<const float4*>(in + j);
    ushort4 o;
    o.x = f2bf(f.x); o.y = f2bf(f.y); o.z = f2bf(f.z); o.w = f2bf(f.w);
    *reinterpret_cast<ushort4*>(out + j) = o;
  }
}

__device__ __forceinline__ void gl_lds16(void* lds, const void* g){
  __builtin_amdgcn_global_load_lds(
      (const __attribute__((address_space(1))) unsigned int*)g,
      (__attribute__((address_space(3))) unsigned int*)lds, 16, 0, 0);
}

// ---------------------------------------------------------------------------
// GEMM (unchanged from R15 — best measured): 256x128 tile, BK=32, 8 waves as
// 4Mx2N, 3 x 24KB LDS buffers (2 blocks/CU), prefetch distance 2, single
// barrier per K-step, counted vmcnt(3), swizzle byte ^= ((row>>1)&3)<<4.
// ---------------------------------------------------------------------------
#define GBUF 12288   // u16 per buffer (24KB): A 16KB + B 8KB

template<int MODE>
__device__ __forceinline__ void gemm_core(const u16* __restrict__ A, const u16* __restrict__ W,
                                          const float* __restrict__ bias, void* __restrict__ outp,
                                          float cscale, int bx, int by, u16* gsm){
  const int tid = threadIdx.x;
  const int wid = tid >> 6, lane = tid & 63;
  const int wm = wid >> 1, wn = wid & 1;     // 4M x 2N wave grid
  const int g = lane >> 4, r = lane & 15;

  const int srow = tid >> 2;
  const int sc = ((tid & 3) * 16) ^ (((srow >> 1) & 3) << 4);
  const u16* Ag = A + ((size_t)(bx * 256) + srow) * DMODEL + (sc >> 1);
  const u16* Bg = W + ((size_t)(by * 128) + srow) * DMODEL + (sc >> 1);
  const int ldsw = wid * 1024;

  f32x4 acc[4][4];
  #pragma unroll
  for (int m = 0; m < 4; ++m)
    #pragma unroll
    for (int n = 0; n < 4; ++n) acc[m][n] = (f32x4){0,0,0,0};

  const int NK = DMODEL / 32;

  auto STAGE = [&](int b, int tk){
    char* ab = (char*)(gsm + b * GBUF);
    char* bb = (char*)(gsm + b * GBUF + 8192);
    const int ke = tk * 32;
    gl_lds16(ab + ldsw,        (const char*)(Ag + ke));
    gl_lds16(ab + 8192 + ldsw, (const char*)(Ag + (size_t)128 * DMODEL + ke));
    gl_lds16(bb + ldsw,        (const char*)(Bg + ke));
  };

  STAGE(0, 0); STAGE(1, 1);

  int cur = 0;
  for (int t = 0; t < NK; ++t){
    if (t < NK - 1) asm volatile("s_waitcnt vmcnt(3)" ::: "memory");
    else            asm volatile("s_waitcnt vmcnt(0)" ::: "memory");
    __builtin_amdgcn_sched_barrier(0);
    __builtin_amdgcn_s_barrier();
    __builtin_amdgcn_sched_barrier(0);

    if (t + 2 < NK){
      int nb = cur + 2; if (nb >= 3) nb -= 3;
      STAGE(nb, t + 2);
    }

    const char* ab = (const char*)(gsm + cur * GBUF);
    const char* bb = (const char*)(gsm + cur * GBUF + 8192);

    short8 af[4], bf[4];
    #pragma unroll
    for (int mt = 0; mt < 4; ++mt){
      const int ar = wm * 64 + mt * 16 + r;
      af[mt] = *reinterpret_cast<const short8*>(
          ab + ar * 64 + ((g * 16) ^ (((ar >> 1) & 3) << 4)));
    }
    #pragma unroll
    for (int nt = 0; nt < 4; ++nt){
      const int br = wn * 64 + nt * 16 + r;
      bf[nt] = *reinterpret_cast<const short8*>(
          bb + br * 64 + ((g * 16) ^ (((br >> 1) & 3) << 4)));
    }

    __builtin_amdgcn_s_setprio(1);
    #pragma unroll
    for (int mt = 0; mt < 4; ++mt)
      #pragma unroll
      for (int nt = 0; nt < 4; ++nt)
        acc[mt][nt] = __builtin_amdgcn_mfma_f32_16x16x32_bf16(af[mt], bf[nt], acc[mt][nt], 0, 0, 0);
    __builtin_amdgcn_s_setprio(0);

    ++cur; if (cur == 3) cur = 0;
  }

  #pragma unroll
  for (int nt = 0; nt < 4; ++nt){
    const int col = by * 128 + wn * 64 + nt * 16 + r;
    const float bv = bias[col];
    #pragma unroll
    for (int mt = 0; mt < 4; ++mt){
      #pragma unroll
      for (int qi = 0; qi < 4; ++qi){
        const int row = bx * 256 + wm * 64 + mt * 16 + g * 4 + qi;
        if (MODE == 0){
          ((u16*)outp)[(size_t)(col >> 7) * (L * DHEAD) + (size_t)row * DHEAD + (col & 127)]
              = f2bf((acc[mt][nt][qi] + bv) * cscale);
        } else if (MODE == 1){
          ((u16*)outp)[(size_t)(col >> 7) * (DHEAD * L) + (size_t)(col & 127) * L + row]
              = f2bf(acc[mt][nt][qi] + bv);
        } else {
          ((float*)outp)[(size_t)row * DMODEL + col] = acc[mt][nt][qi] + bv;
        }
      }
    }
  }
}

__global__ __launch_bounds__(512, 4) void gemm_qkv(const u16* __restrict__ A,
    const u16* __restrict__ Wq, const u16* __restrict__ Wk, const u16* __restrict__ Wv,
    const float* __restrict__ bq, const float* __restrict__ bk, const float* __restrict__ bv,
    u16* __restrict__ Qb, u16* __restrict__ Kb, u16* __restrict__ Vtb){
  extern __shared__ u16 gsm[];
  const int sel = blockIdx.y >> 4;
  const int byl = blockIdx.y & 15;
  const u16* W      = (sel == 0) ? Wq : (sel == 1) ? Wk : Wv;
  const float* bias = (sel == 0) ? bq : (sel == 1) ? bk : bv;
  if (sel < 2)
    gemm_core<0>(A, W, bias, (sel == 0) ? (void*)Qb : (void*)Kb,
                 (sel == 0) ? QSCALE : 1.0f, blockIdx.x, byl, gsm);
  else
    gemm_core<1>(A, W, bias, (void*)Vtb, 1.0f, blockIdx.x, byl, gsm);
}

__global__ __launch_bounds__(512, 4) void gemm_o(const u16* __restrict__ A, const u16* __restrict__ W,
                                                 const float* __restrict__ bias, float* __restrict__ outp){
  extern __shared__ u16 gsm[];
  gemm_core<2>(A, W, bias, (void*)outp, 1.0f, blockIdx.x, blockIdx.y, gsm);
}

// ---------------------------------------------------------------------------
// Attention: R13/R15 base + T15 att[2] pipeline: PV[t-1] runs inside tile t,
// off the QK[t]->softmax[t] critical path (independent MFMAs fill the matrix
// pipe while VALU waits on QK results). V triple-buffered so V[t-1] survives
// the V[t+1] staging. LDS 80 KiB: K 2x16K + V 3x16K. 2 blocks/CU.
// ---------------------------------------------------------------------------

__device__ __forceinline__ void stage_K64(u16* buf, const u16* Kh, int kv0, int wid, int lane){
  #pragma unroll
  for (int i = 0; i < 4; ++i){
    int ib = (wid * 4 + i) * 1024;
    int off = ib + lane * 16;
    int row = off >> 8;
    int c = off & 255;
    int sc = c ^ ((row & 7) << 4);
    gl_lds16((char*)buf + ib, (const char*)(Kh + (size_t)(kv0 + row) * DHEAD) + sc);
  }
}

__device__ __forceinline__ void stage_V64(u16* buf, const u16* Vh, int kv0, int wid, int lane){
  #pragma unroll
  for (int i = 0; i < 4; ++i){
    int ib = (wid * 4 + i) * 1024;
    int off = ib + lane * 16;
    int row = off >> 7;
    int c = off & 127;
    int sc = c ^ ((row & 7) << 4);
    gl_lds16((char*)buf + ib, (const char*)(Vh + (size_t)row * L + kv0) + sc);
  }
}

// Fixed-reference softmax (S-16 via MFMA C-init, exp2 domain) producing the
// PV A-fragments directly in registers (cvt_pk + permlane swaps).
__device__ __forceinline__ void sm_R(f32x4 (&s)[4], float &l, bool dg, int qrow,
                                     int kv0, int g, u32 (&paw)[2][4]){
  if (dg){
    #pragma unroll
    for (int cb = 0; cb < 4; ++cb){
      int kvb = kv0 + cb * 16 + g * 4;
      #pragma unroll
      for (int e = 0; e < 4; ++e)
        if (kvb + e > qrow) s[cb][e] = -1e30f;
    }
  }
  float rs = 0.f;
  u32 pk[4][2];
  #pragma unroll
  for (int cb = 0; cb < 4; ++cb){
    float p0 = __builtin_amdgcn_exp2f(s[cb][0]);
    float p1 = __builtin_amdgcn_exp2f(s[cb][1]);
    float p2 = __builtin_amdgcn_exp2f(s[cb][2]);
    float p3 = __builtin_amdgcn_exp2f(s[cb][3]);
    rs += (p0 + p1) + (p2 + p3);
    pk[cb][0] = cvtpk(p0, p1);
    pk[cb][1] = cvtpk(p2, p3);
  }
  rs += __shfl_xor(rs, 16);
  rs += __shfl_xor(rs, 32);
  l += rs;
  #pragma unroll
  for (int ks = 0; ks < 2; ++ks){
    #pragma unroll
    for (int h = 0; h < 2; ++h){
      u32 a = pk[ks * 2][h], b = pk[ks * 2 + 1][h];
      asm volatile("v_permlane32_swap_b32 %0, %1" : "+v"(a), "+v"(b));
      asm volatile("v_permlane16_swap_b32 %0, %1" : "+v"(a), "+v"(b));
      paw[ks][h] = a;
      paw[ks][2 + h] = b;
    }
  }
}

__global__ __launch_bounds__(256, 2) void attn_kernel(const u16* __restrict__ Q, const u16* __restrict__ Km,
                                                      const u16* __restrict__ Vt, u16* __restrict__ Ob,
                                                      const int* __restrict__ is_causal_p){
  extern __shared__ u16 smem[];
  u16* Ks  = smem;            // 2 x 8192 u16 = 32 KiB
  u16* Vsm = smem + 16384;    // 3 x 8192 u16 = 48 KiB

  const int lane = threadIdx.x & 63, wid = threadIdx.x >> 6;
  const int g = lane >> 4, r = lane & 15;

  int lg = (blockIdx.x & 7) * 64 + (blockIdx.x >> 3);
  int head = lg >> 5;
  int raw = lg & 31;
  int j = (head & 1) ? (31 - raw) : raw;
  const int jA = j, jB = 63 - j;
  const int causal = *is_causal_p;
  const int nt = causal ? (jB + 1) : 64;

  const u16* Qh = Q  + (size_t)head * L * DHEAD;
  const u16* Kh = Km + (size_t)head * L * DHEAD;
  const u16* Vh = Vt + (size_t)head * DHEAD * L;

  const int rowA = 64 * jA + wid * 16;
  const int rowB = 64 * jB + wid * 16;

  short8 qf[2][4];
  #pragma unroll
  for (int kb = 0; kb < 4; ++kb){
    qf[0][kb] = *reinterpret_cast<const short8*>(&Qh[(size_t)(rowA + r) * DHEAD + kb * 32 + g * 8]);
    qf[1][kb] = *reinterpret_cast<const short8*>(&Qh[(size_t)(rowB + r) * DHEAD + kb * 32 + g * 8]);
  }

  f32x4 o[2][8];
  #pragma unroll
  for (int m = 0; m < 2; ++m)
    #pragma unroll
    for (int db = 0; db < 8; ++db) o[m][db] = (f32x4){0.f, 0.f, 0.f, 0.f};
  float lA = 0.f, lB = 0.f;

  stage_K64(Ks,  Kh, 0, wid, lane);
  stage_V64(Vsm, Vh, 0, wid, lane);   // V[0] -> buf 0

  // Deferred-PV state: fragments of tile t-1, consumed during tile t.
  u32 pawA_p[2][4], pawB_p[2][4];
  bool pActA = false;

  // PV for tile tp (reads V buf tp%3, accumulates into o).
  auto PV = [&](int tp, bool pA){
    const char* Vb = (const char*)(Vsm + (tp % 3) * 8192);
    __builtin_amdgcn_s_setprio(1);
    #pragma unroll
    for (int st = 0; st < 2; ++st){
      union { u32 u[4]; short8 v; } pa0, pa1;
      #pragma unroll
      for (int w = 0; w < 4; ++w){ pa0.u[w] = pawA_p[st][w]; pa1.u[w] = pawB_p[st][w]; }
      #pragma unroll
      for (int db = 0; db < 8; ++db){
        const int rv = db * 16 + r;
        short8 vf = *reinterpret_cast<const short8*>(
            Vb + rv * 128 + (((st * 32 + g * 8) * 2) ^ ((rv & 7) << 4)));
        if (pA)
          o[0][db] = __builtin_amdgcn_mfma_f32_16x16x32_bf16(pa0.v, vf, o[0][db], 0, 0, 0);
        o[1][db] = __builtin_amdgcn_mfma_f32_16x16x32_bf16(pa1.v, vf, o[1][db], 0, 0, 0);
      }
    }
    __builtin_amdgcn_s_setprio(0);
  };

  for (int t = 0; t < nt; ++t){
    const int kv0 = t * 64;
    const bool actA = (!causal) || (t <= jA);
    const bool dgA = causal && (t == jA);
    const bool dgB = causal && (t == jB);

    // K[t],V[t] were issued one iteration ago (or prologue) — drain + sync.
    asm volatile("s_waitcnt vmcnt(0)" ::: "memory");
    __builtin_amdgcn_sched_barrier(0);
    __builtin_amdgcn_s_barrier();
    __builtin_amdgcn_sched_barrier(0);

    if (t + 1 < nt){
      stage_K64(Ks  + ((t + 1) & 1) * 8192, Kh, kv0 + 64, wid, lane);
      stage_V64(Vsm + ((t + 1) % 3) * 8192, Vh, kv0 + 64, wid, lane);
    }

    const char* Kb = (const char*)(Ks + (t & 1) * 8192);

    // ---- QK[t]: S - 16 via accumulator init; swapped operands ----
    f32x4 s[2][4];
    #pragma unroll
    for (int m = 0; m < 2; ++m)
      #pragma unroll
      for (int cb = 0; cb < 4; ++cb) s[m][cb] = (f32x4){-16.f, -16.f, -16.f, -16.f};
    __builtin_amdgcn_s_setprio(1);
    #pragma unroll
    for (int cb = 0; cb < 4; ++cb){
      const int rr = cb * 16 + r;
      short8 kf[4];
      #pragma unroll
      for (int kb = 0; kb < 4; ++kb)
        kf[kb] = *reinterpret_cast<const short8*>(
            Kb + rr * 256 + ((kb * 64 + g * 16) ^ ((rr & 7) << 4)));
      if (actA){
        #pragma unroll
        for (int kb = 0; kb < 4; ++kb)
          s[0][cb] = __builtin_amdgcn_mfma_f32_16x16x32_bf16(kf[kb], qf[0][kb], s[0][cb], 0, 0, 0);
      }
      #pragma unroll
      for (int kb = 0; kb < 4; ++kb)
        s[1][cb] = __builtin_amdgcn_mfma_f32_16x16x32_bf16(kf[kb], qf[1][kb], s[1][cb], 0, 0, 0);
    }
    __builtin_amdgcn_s_setprio(0);

    // ---- PV[t-1]: independent of s[t]; fills MFMA pipe under softmax ----
    if (t > 0) PV(t - 1, pActA);

    // ---- softmax[t] -> fresh paw fragments ----
    u32 pawA_c[2][4], pawB_c[2][4];
    if (actA) sm_R(s[0], lA, dgA, rowA + r, kv0, g, pawA_c);
    sm_R(s[1], lB, dgB, rowB + r, kv0, g, pawB_c);

    #pragma unroll
    for (int ks = 0; ks < 2; ++ks)
      #pragma unroll
      for (int w = 0; w < 4; ++w){
        pawA_p[ks][w] = pawA_c[ks][w];
        pawB_p[ks][w] = pawB_c[ks][w];
      }
    pActA = actA;
  }

  // Drain the pipeline: PV for the final tile.
  PV(nt - 1, pActA);

  #pragma unroll
  for (int m = 0; m < 2; ++m){
    const int rbase = m ? rowB : rowA;
    const float lv = m ? lB : lA;
    float lb[4];
    #pragma unroll
    for (int qi = 0; qi < 4; ++qi) lb[qi] = __shfl(lv, g * 4 + qi);
    #pragma unroll
    for (int db = 0; db < 8; ++db)
      #pragma unroll
      for (int qi = 0; qi < 4; ++qi){
        float val = o[m][db][qi] / lb[qi];
        int qrow = rbase + g * 4 + qi;
        Ob[(size_t)qrow * DMODEL + head * DHEAD + db * 16 + r] = f2bf(val);
      }
  }
}

extern "C" void kernel_launch(void* const* d_in, const int* in_sizes, int n_in,
                              void* d_out, int out_size, void* d_ws, size_t ws_size,
                              hipStream_t stream){
  const float* X  = (const float*)d_in[0];
  const float* Wq = (const float*)d_in[1];
  const float* bq = (const float*)d_in[2];
  const float* Wk = (const float*)d_in[3];
  const float* bk = (const float*)d_in[4];
  const float* Wv = (const float*)d_in[5];
  const float* bv = (const float*)d_in[6];
  const float* Wo = (const float*)d_in[7];
  const float* bo = (const float*)d_in[8];
  const int*   isc = (const int*)d_in[9];

  char* ws = (char*)d_ws;
  u16* Xb  = (u16*)(ws);              // 16 MiB, reused as Ob after attention
  u16* Qb  = (u16*)(ws + 16777216);
  u16* Kb  = (u16*)(ws + 33554432);
  u16* Vtb = (u16*)(ws + 50331648);
  u16* Wqb = (u16*)(ws + 67108864);
  u16* Wkb = (u16*)(ws + 75497472);
  u16* Wvb = (u16*)(ws + 83886080);
  u16* Wob = (u16*)(ws + 92274688);
  u16* Ob  = Xb;

  (void)hipFuncSetAttribute(reinterpret_cast<const void*>(attn_kernel),
                            hipFuncAttributeMaxDynamicSharedMemorySize, 81920);
  (void)hipFuncSetAttribute(reinterpret_cast<const void*>(gemm_qkv),
                            hipFuncAttributeMaxDynamicSharedMemorySize, 73728);
  (void)hipFuncSetAttribute(reinterpret_cast<const void*>(gemm_o),
                            hipFuncAttributeMaxDynamicSharedMemorySize, 73728);

  cast_all_kernel<<<dim3(1024, 5), 256, 0, stream>>>(X, Xb, Wq, Wk, Wv, Wo,
                                                     Wqb, Wkb, Wvb, Wob);

  gemm_qkv<<<dim3(16, 48), 512, 73728, stream>>>(Xb, Wqb, Wkb, Wvb, bq, bk, bv, Qb, Kb, Vtb);

  attn_kernel<<<512, 256, 81920, stream>>>(Qb, Kb, Vtb, Ob, isc);

  gemm_o<<<dim3(16, 16), 512, 73728, stream>>>(Ob, Wob, bo, (float*)d_out);
}